// Round 1
// baseline (1693.815 us; speedup 1.0000x reference)
//
#include <hip/hip_runtime.h>

// Dims
#define NB 4
#define NTOK 32768
#define BNT 131072      // NB*NTOK
#define CDIM 256
#define HH 8
#define DD 32
#define SS 64
#define NCOL 768        // 256 fx cols + 512 proj cols

// ---------------- K0: build combined weight matrix ----------------
// Bcomb (256 x 768): cols [0,256) = Wfx^T ; cols [256,768) = Wx^T @ Wslice^T per head
// bcomb (768): [bfx | bslice + bx_h @ Wslice^T]
__global__ __launch_bounds__(256) void k0_build(
    const float* __restrict__ Wx, const float* __restrict__ bx,
    const float* __restrict__ Wfx, const float* __restrict__ bfx,
    const float* __restrict__ Wslice, const float* __restrict__ bslice,
    float* __restrict__ Bcomb, float* __restrict__ bcomb)
{
    int col = blockIdx.x;      // 0..767
    int k = threadIdx.x;       // 0..255
    if (col < 256) {
        Bcomb[k * NCOL + col] = Wfx[col * 256 + k];
        if (k == 0) bcomb[col] = bfx[col];
    } else {
        int p = col - 256, h = p >> 6, s = p & 63;
        float acc = 0.f;
        #pragma unroll
        for (int d = 0; d < 32; ++d)
            acc += Wx[(h * 32 + d) * 256 + k] * Wslice[s * 32 + d];
        Bcomb[k * NCOL + col] = acc;
        if (k == 0) {
            float bacc = bslice[s];
            #pragma unroll
            for (int d = 0; d < 32; ++d)
                bacc += bx[h * 32 + d] * Wslice[s * 32 + d];
            bcomb[col] = bacc;
        }
    }
}

// ---------------- generic tiled fp32 GEMM: C = A*B + bias ----------------
// BM=BN=BK=64, 256 threads, 4x4 micro-tile per thread. Dims must divide 64.
__global__ __launch_bounds__(256) void sgemm64(
    const float* __restrict__ A, const float* __restrict__ Bm,
    const float* __restrict__ bias, float* __restrict__ Cm,
    int K, int lda, int ldb, int ldc,
    long strideA, long strideB, long strideC)
{
    int bz = blockIdx.z;
    A  += (long)bz * strideA;
    Bm += (long)bz * strideB;
    Cm += (long)bz * strideC;
    int m0 = blockIdx.y * 64, n0 = blockIdx.x * 64;

    __shared__ float As[64][68];  // As[k][m]  (transposed A tile)
    __shared__ float Bs[64][68];  // Bs[k][n]

    int tid = threadIdx.x;
    int tx = tid & 15, ty = tid >> 4;

    float acc[4][4] = {};

    for (int k0 = 0; k0 < K; k0 += 64) {
        // load A tile (64 m x 64 k), transpose into As[k][m]
        #pragma unroll
        for (int i = 0; i < 4; ++i) {
            int m = (tid >> 4) + i * 16;
            int kk = (tid & 15) * 4;
            float4 a4 = *(const float4*)&A[(long)(m0 + m) * lda + k0 + kk];
            As[kk + 0][m] = a4.x;
            As[kk + 1][m] = a4.y;
            As[kk + 2][m] = a4.z;
            As[kk + 3][m] = a4.w;
        }
        // load B tile (64 k x 64 n)
        #pragma unroll
        for (int i = 0; i < 4; ++i) {
            int kk = (tid >> 4) + i * 16;
            int n = (tid & 15) * 4;
            float4 b4 = *(const float4*)&Bm[(long)(k0 + kk) * ldb + n0 + n];
            *(float4*)&Bs[kk][n] = b4;
        }
        __syncthreads();
        #pragma unroll 16
        for (int kk = 0; kk < 64; ++kk) {
            float4 a = *(const float4*)&As[kk][ty * 4];
            float4 b = *(const float4*)&Bs[kk][tx * 4];
            float av[4] = {a.x, a.y, a.z, a.w};
            float bv[4] = {b.x, b.y, b.z, b.w};
            #pragma unroll
            for (int i = 0; i < 4; ++i)
                #pragma unroll
                for (int j = 0; j < 4; ++j)
                    acc[i][j] += av[i] * bv[j];
        }
        __syncthreads();
    }

    float4 bi = *(const float4*)&bias[n0 + tx * 4];
    float bvv[4] = {bi.x, bi.y, bi.z, bi.w};
    #pragma unroll
    for (int i = 0; i < 4; ++i) {
        float4 o;
        o.x = acc[i][0] + bvv[0];
        o.y = acc[i][1] + bvv[1];
        o.z = acc[i][2] + bvv[2];
        o.w = acc[i][3] + bvv[3];
        *(float4*)&Cm[(long)(m0 + ty * 4 + i) * ldc + n0 + tx * 4] = o;
    }
}

// ---------------- K1b: in-place softmax over 64 slices per (token, head) ----------------
__global__ __launch_bounds__(256) void k1b_softmax(
    float* __restrict__ y, const float* __restrict__ temperature)
{
    long unit = (long)blockIdx.x * 4 + (threadIdx.x >> 6);  // (token*8 + head)
    int lane = threadIdx.x & 63;
    long t = unit >> 3;
    int h = (int)(unit & 7);
    float temp = fminf(fmaxf(temperature[h], 0.5f), 5.0f);
    float* p = y + t * NCOL + 256 + h * 64 + lane;
    float v = (*p) / temp;
    float m = v;
    #pragma unroll
    for (int o = 32; o; o >>= 1) m = fmaxf(m, __shfl_xor(m, o));
    float e = __expf(v - m);
    float ss = e;
    #pragma unroll
    for (int o = 32; o; o >>= 1) ss += __shfl_xor(ss, o);
    *p = e / ss;
}

// ---------------- K1c: accumulate slice_token partials + slice_norm partials ----------------
// grid: 32 (b,h) * 64 chunks; each block: 512 tokens; partials[bh][chunk][64*32 + 64]
__global__ __launch_bounds__(256) void k1c_accum(
    const float* __restrict__ y, float* __restrict__ partials)
{
    int chunk = blockIdx.x & 63;
    int bh = blockIdx.x >> 6;
    int b = bh >> 3, h = bh & 7;
    long tbase = (long)b * NTOK + (long)chunk * 512;

    __shared__ float wl[8][64];
    __shared__ float fxl[8][32];

    int tid = threadIdx.x;
    int d = tid & 31;
    int sg = tid >> 5;  // 0..7

    float acc[8] = {0, 0, 0, 0, 0, 0, 0, 0};
    float nacc = 0.f;

    for (int g = 0; g < 64; ++g) {
        long t0 = tbase + g * 8;
        // stage 8 tokens: w rows (8x64) and fx rows (8x32)
        {
            int idx = tid;
            #pragma unroll
            for (int r = 0; r < 2; ++r, idx += 256) {
                int ti = idx >> 6, s = idx & 63;
                wl[ti][s] = y[(t0 + ti) * NCOL + 256 + h * 64 + s];
            }
            int ti = tid >> 5, dd = tid & 31;
            fxl[ti][dd] = y[(t0 + ti) * NCOL + h * 32 + dd];
        }
        __syncthreads();
        #pragma unroll
        for (int ti = 0; ti < 8; ++ti) {
            float f = fxl[ti][d];
            #pragma unroll
            for (int k = 0; k < 8; ++k)
                acc[k] += wl[ti][sg + 8 * k] * f;
        }
        if (tid < 64) {
            #pragma unroll
            for (int ti = 0; ti < 8; ++ti) nacc += wl[ti][tid];
        }
        __syncthreads();
    }

    float* P = partials + ((long)bh * 64 + chunk) * 2112;
    #pragma unroll
    for (int k = 0; k < 8; ++k) {
        int s = sg + 8 * k;
        P[s * 32 + d] = acc[k];
    }
    if (tid < 64) P[2048 + tid] = nacc;
}

// ---------------- K3: reduce partials, slice attention, build OT2 ----------------
// OT2[b][(h*64+s)][c] = sum_d out_tok[b,h,s,d] * Wout[c][h*32+d]
__global__ __launch_bounds__(256) void k3_slice(
    const float* __restrict__ partials,
    const float* __restrict__ Wqkv,
    const float* __restrict__ Wout,
    float* __restrict__ OT2)
{
    __shared__ float smem[14720];
    float* st = smem;          // 64*33
    float* q  = smem + 2112;   // 64*33
    float* kk = smem + 4224;   // 64*33
    float* v  = smem + 6336;   // 64*33
    float* L  = smem + 8448;   // 64*65 = 4160
    float* red = L;            // 2112 (phase 1 only)
    float* ot = smem + 12608;  // 64*33

    int bh = blockIdx.x;
    int b = bh >> 3, h = bh & 7;
    int tid = threadIdx.x;

    // 1: deterministic reduce over 64 chunks
    for (int idx = tid; idx < 2112; idx += 256) {
        float s = 0.f;
        const float* P = partials + (long)bh * 64 * 2112 + idx;
        for (int c = 0; c < 64; ++c) s += P[c * 2112];
        red[idx] = s;
    }
    __syncthreads();
    // 2: slice_token = unnorm / (norm + 0.01)
    for (int idx = tid; idx < 2048; idx += 256) {
        int s = idx >> 5, d = idx & 31;
        st[s * 33 + d] = red[idx] / (red[2048 + s] + 0.01f);
    }
    __syncthreads();
    // 3: qkv = slice_token @ Wqkv^T
    for (int idx = tid; idx < 64 * 96; idx += 256) {
        int s = idx / 96, e = idx % 96;
        float acc = 0.f;
        #pragma unroll
        for (int d = 0; d < 32; ++d) acc += st[s * 33 + d] * Wqkv[e * 32 + d];
        if (e < 32)       q[s * 33 + e] = acc;
        else if (e < 64)  kk[s * 33 + (e - 32)] = acc;
        else              v[s * 33 + (e - 64)] = acc;
    }
    __syncthreads();
    // 4: logits = q @ k^T * d^-0.5
    for (int idx = tid; idx < 4096; idx += 256) {
        int i = idx >> 6, j = idx & 63;
        float acc = 0.f;
        #pragma unroll
        for (int d = 0; d < 32; ++d) acc += q[i * 33 + d] * kk[j * 33 + d];
        L[i * 65 + j] = acc * 0.17677669529663687f;
    }
    __syncthreads();
    // 5: row softmax (4 waves, 16 rows each)
    {
        int lane = tid & 63, wid = tid >> 6;
        for (int r = wid; r < 64; r += 4) {
            float x = L[r * 65 + lane];
            float m = x;
            #pragma unroll
            for (int o = 32; o; o >>= 1) m = fmaxf(m, __shfl_xor(m, o));
            float e = __expf(x - m);
            float ss2 = e;
            #pragma unroll
            for (int o = 32; o; o >>= 1) ss2 += __shfl_xor(ss2, o);
            L[r * 65 + lane] = e / ss2;
        }
    }
    __syncthreads();
    // 6: out_tok = attn @ v
    for (int idx = tid; idx < 2048; idx += 256) {
        int s = idx >> 5, d = idx & 31;
        float acc = 0.f;
        #pragma unroll
        for (int j = 0; j < 64; ++j) acc += L[s * 65 + j] * v[j * 33 + d];
        ot[s * 33 + d] = acc;
    }
    __syncthreads();
    // 7: stage Wout head-block (overwrites st/q/k/v — all dead now)
    float* Wo = smem;  // 256*33 = 8448 floats
    for (int idx = tid; idx < 8192; idx += 256) {
        int c = idx >> 5, d = idx & 31;
        Wo[c * 33 + d] = Wout[c * 256 + h * 32 + d];
    }
    __syncthreads();
    // 8: OT2[b][(h*64+s)][c]
    {
        int c = tid;
        float* O = OT2 + ((long)b * 512 + h * 64) * 256;
        for (int s = 0; s < 64; ++s) {
            float acc = 0.f;
            #pragma unroll
            for (int d = 0; d < 32; ++d) acc += ot[s * 33 + d] * Wo[c * 33 + d];
            O[s * 256 + c] = acc;
        }
    }
}

extern "C" void kernel_launch(void* const* d_in, const int* in_sizes, int n_in,
                              void* d_out, int out_size, void* d_ws, size_t ws_size,
                              hipStream_t stream) {
    const float* x           = (const float*)d_in[0];
    const float* Wx          = (const float*)d_in[1];
    const float* bx          = (const float*)d_in[2];
    const float* Wfx         = (const float*)d_in[3];
    const float* bfx         = (const float*)d_in[4];
    const float* Wslice      = (const float*)d_in[5];
    const float* bslice      = (const float*)d_in[6];
    const float* Wqkv        = (const float*)d_in[7];
    const float* Wout        = (const float*)d_in[8];
    const float* bout        = (const float*)d_in[9];
    const float* temperature = (const float*)d_in[10];
    float* out = (float*)d_out;

    char* ws = (char*)d_ws;
    float* Bcomb    = (float*)(ws);                                   // 256*768 f32
    float* bcomb    = (float*)(ws + 786432);                          // 768 f32
    float* y        = (float*)(ws + 789504);                          // 131072*768 f32
    float* partials = (float*)(ws + 789504 + 402653184ULL);           // 32*64*2112 f32
    float* OT2      = (float*)(ws + 789504 + 402653184ULL + 17301504ULL); // 4*512*256 f32

    // K0: combined weights
    k0_build<<<768, 256, 0, stream>>>(Wx, bx, Wfx, bfx, Wslice, bslice, Bcomb, bcomb);

    // K1a: y[tok][0:256]=fx, y[tok][256:768]=proj   (M=131072, N=768, K=256)
    sgemm64<<<dim3(NCOL / 64, BNT / 64, 1), 256, 0, stream>>>(
        x, Bcomb, bcomb, y, 256, CDIM, NCOL, NCOL, 0L, 0L, 0L);

    // K1b: softmax over slices in place (proj -> slice_weights)
    k1b_softmax<<<(BNT * HH) / 4, 256, 0, stream>>>(y, temperature);

    // K1c: pooled partial sums
    k1c_accum<<<32 * 64, 256, 0, stream>>>(y, partials);

    // K3: slice attention + OT2
    k3_slice<<<32, 256, 0, stream>>>(partials, Wqkv, Wout, OT2);

    // K4: out = w @ OT2 + bout   (per batch: M=32768, N=256, K=512)
    sgemm64<<<dim3(256 / 64, NTOK / 64, NB), 256, 0, stream>>>(
        y + 256, OT2, bout, out, 512, NCOL, 256, 256,
        (long)NTOK * NCOL, (long)512 * 256, (long)NTOK * 256);
}

// Round 3
// 631.030 us; speedup vs baseline: 2.6842x; 2.6842x over previous
//
#include <hip/hip_runtime.h>

// Dims
#define NB 4
#define NTOK 32768
#define BNT 131072      // NB*NTOK
#define CDIM 256
#define HH 8
#define NCOL 768        // 256 fx cols + 512 proj cols

typedef __attribute__((ext_vector_type(8))) __bf16 bf16x8;
typedef __attribute__((ext_vector_type(4))) __bf16 bf16x4;
typedef __attribute__((ext_vector_type(4))) float f32x4;

__device__ inline void gload_lds16(const void* g, void* l) {
    __builtin_amdgcn_global_load_lds(
        (const __attribute__((address_space(1))) void*)g,
        (__attribute__((address_space(3))) void*)l, 16, 0, 0);
}

// ---------------- K0: build combined weight matrix (bf16 hi/lo, transposed) ----------------
// Bt (768 x 512 bf16): row n = output col; cols [0,256)=hi, [256,512)=lo of
//   Bcomb[k][n] where Bcomb cols [0,256)=Wfx^T, [256,768)=Wx^T@Wslice^T per head.
__global__ __launch_bounds__(256) void k0_build(
    const float* __restrict__ Wx, const float* __restrict__ bx,
    const float* __restrict__ Wfx, const float* __restrict__ bfx,
    const float* __restrict__ Wslice, const float* __restrict__ bslice,
    __bf16* __restrict__ Bt, float* __restrict__ bcomb)
{
    int col = blockIdx.x;      // 0..767 (output column n)
    int k = threadIdx.x;       // 0..255 (input channel)
    float acc;
    if (col < 256) {
        acc = Wfx[col * 256 + k];
        if (k == 0) bcomb[col] = bfx[col];
    } else {
        int p = col - 256, h = p >> 6, s = p & 63;
        acc = 0.f;
        #pragma unroll
        for (int d = 0; d < 32; ++d)
            acc += Wx[(h * 32 + d) * 256 + k] * Wslice[s * 32 + d];
        if (k == 0) {
            float bacc = bslice[s];
            #pragma unroll
            for (int d = 0; d < 32; ++d)
                bacc += bx[h * 32 + d] * Wslice[s * 32 + d];
            bcomb[col] = bacc;
        }
    }
    __bf16 hi = (__bf16)acc;
    Bt[(long)col * 512 + k] = hi;
    Bt[(long)col * 512 + 256 + k] = (__bf16)(acc - (float)hi);
}

// ---------------- split-bf16 MFMA GEMM (+ optional fused slice-softmax) ----------------
// C[m][n] = sum_k A[m][k]*B[k][n] + bias[n], A fp32 (lda), Bt bf16 [N][2*KO]
// (row n holds hi at [0,KO), lo at [KO,2KO)). 3-term split: hi*hi+lo*hi+hi*lo.
// 128x128 tile, 4 waves (2x2), 16x16x32 bf16 MFMA, XOR-swizzled LDS.
// FUSE_SM: cols >=256 get temperature-scaled softmax over each 64-col head block.
template<int NSO, bool FUSE_SM>   // K-steps of 64: K1a NSO=4 (K=256), K4 NSO=8 (K=512)
__global__ __launch_bounds__(256) void gemm_split(
    const float* __restrict__ A, const __bf16* __restrict__ Bt,
    const float* __restrict__ bias, float* __restrict__ C,
    const float* __restrict__ temperature,
    int lda, int ldc, long bStrideB)
{
    constexpr int KO = NSO * 64;
    __shared__ __bf16 sAhi[128 * 64];
    __shared__ __bf16 sAlo[128 * 64];
    __shared__ __bf16 sBhi[128 * 64];
    __shared__ __bf16 sBlo[128 * 64];

    const int tid = threadIdx.x;
    const int lane = tid & 63;
    const int w = tid >> 6;
    const int wr = w >> 1, wc = w & 1;
    const int m0 = blockIdx.y * 128, n0 = blockIdx.x * 128;
    const __bf16* BtB = Bt + ((long)m0 >> 15) * bStrideB;  // per-batch B (K4)

    f32x4 acc[4][4] = {};

    for (int cs = 0; cs < NSO; ++cs) {
        __syncthreads();   // previous compute done; LDS reusable
        // --- stage B hi+lo tiles via global_load_lds, source pre-swizzled ---
        {
            const __bf16* bhiBase = BtB + cs * 64;
            const __bf16* bloBase = BtB + KO + cs * 64;
            #pragma unroll
            for (int i = 0; i < 4; ++i) {
                int li = i * 256 + tid;
                int r = li >> 3, c = li & 7;
                int csrc = c ^ (r & 7);
                long go = (long)(n0 + r) * (2 * KO) + csrc * 8;
                int lb = (i * 256 + (tid & ~63)) * 16;   // wave-uniform base
                gload_lds16(bhiBase + go, (char*)sBhi + lb);
                gload_lds16(bloBase + go, (char*)sBlo + lb);
            }
        }
        // --- stage A: fp32 -> (hi,lo) bf16, swizzled ds_write ---
        // tile = 128 rows x 64 k = 2048 float4 chunks; 8 iters x 256 threads
        {
            #pragma unroll
            for (int i = 0; i < 8; ++i) {
                int li = i * 256 + tid;
                int r = li >> 4, q = li & 15;   // q: 4-float chunk within row
                float4 v = *(const float4*)(A + (long)(m0 + r) * lda + cs * 64 + q * 4);
                __bf16 h0 = (__bf16)v.x, h1 = (__bf16)v.y,
                       h2 = (__bf16)v.z, h3 = (__bf16)v.w;
                __bf16 l0 = (__bf16)(v.x - (float)h0), l1 = (__bf16)(v.y - (float)h1),
                       l2 = (__bf16)(v.z - (float)h2), l3 = (__bf16)(v.w - (float)h3);
                int byteoff = r * 128 + ((((q >> 1) ^ (r & 7)) << 4)) + (q & 1) * 8;
                *(bf16x4*)((char*)sAhi + byteoff) = (bf16x4){h0, h1, h2, h3};
                *(bf16x4*)((char*)sAlo + byteoff) = (bf16x4){l0, l1, l2, l3};
            }
        }
        __syncthreads();   // drains vmcnt (gload_lds) + lgkmcnt (ds_write)
        // --- compute: 2 k-subs x 16 frag-pairs x 3 MFMAs ---
        #pragma unroll
        for (int ksub = 0; ksub < 2; ++ksub) {
            int cr = ksub * 4 + (lane >> 4);
            bf16x8 ah[4], al[4], bh[4], bl[4];
            #pragma unroll
            for (int mi = 0; mi < 4; ++mi) {
                int r = wr * 64 + mi * 16 + (lane & 15);
                int off = r * 128 + ((cr ^ (r & 7)) << 4);
                ah[mi] = *(const bf16x8*)((const char*)sAhi + off);
                al[mi] = *(const bf16x8*)((const char*)sAlo + off);
            }
            #pragma unroll
            for (int ni = 0; ni < 4; ++ni) {
                int r = wc * 64 + ni * 16 + (lane & 15);
                int off = r * 128 + ((cr ^ (r & 7)) << 4);
                bh[ni] = *(const bf16x8*)((const char*)sBhi + off);
                bl[ni] = *(const bf16x8*)((const char*)sBlo + off);
            }
            #pragma unroll
            for (int mi = 0; mi < 4; ++mi)
                #pragma unroll
                for (int ni = 0; ni < 4; ++ni) {
                    acc[mi][ni] = __builtin_amdgcn_mfma_f32_16x16x32_bf16(ah[mi], bh[ni], acc[mi][ni], 0, 0, 0);
                    acc[mi][ni] = __builtin_amdgcn_mfma_f32_16x16x32_bf16(al[mi], bh[ni], acc[mi][ni], 0, 0, 0);
                    acc[mi][ni] = __builtin_amdgcn_mfma_f32_16x16x32_bf16(ah[mi], bl[ni], acc[mi][ni], 0, 0, 0);
                }
        }
    }
    // --- epilogue: C/D layout col=lane&15, row=(lane>>4)*4+reg ---
    {
        int rbase = m0 + wr * 64 + (lane >> 4) * 4;
        int cbase = n0 + wc * 64 + (lane & 15);
        float bv[4];
        #pragma unroll
        for (int ni = 0; ni < 4; ++ni) bv[ni] = bias[cbase + ni * 16];

        bool proj = FUSE_SM && (n0 + wc * 64) >= 256;   // wave-uniform
        if (proj) {
            int h = (n0 + wc * 64 - 256) >> 6;
            float invt = 1.f / fminf(fmaxf(temperature[h], 0.5f), 5.0f);
            #pragma unroll
            for (int mi = 0; mi < 4; ++mi)
                #pragma unroll
                for (int rr = 0; rr < 4; ++rr) {
                    float v[4];
                    #pragma unroll
                    for (int ni = 0; ni < 4; ++ni)
                        v[ni] = (acc[mi][ni][rr] + bv[ni]) * invt;
                    float m = fmaxf(fmaxf(v[0], v[1]), fmaxf(v[2], v[3]));
                    #pragma unroll
                    for (int o = 1; o < 16; o <<= 1) m = fmaxf(m, __shfl_xor(m, o));
                    float e[4], s = 0.f;
                    #pragma unroll
                    for (int ni = 0; ni < 4; ++ni) { e[ni] = __expf(v[ni] - m); s += e[ni]; }
                    #pragma unroll
                    for (int o = 1; o < 16; o <<= 1) s += __shfl_xor(s, o);
                    float rs = 1.f / s;
                    long row = rbase + mi * 16 + rr;
                    #pragma unroll
                    for (int ni = 0; ni < 4; ++ni)
                        C[row * ldc + cbase + ni * 16] = e[ni] * rs;
                }
        } else {
            #pragma unroll
            for (int mi = 0; mi < 4; ++mi)
                #pragma unroll
                for (int ni = 0; ni < 4; ++ni)
                    #pragma unroll
                    for (int rr = 0; rr < 4; ++rr)
                        C[(long)(rbase + mi * 16 + rr) * ldc + cbase + ni * 16] =
                            acc[mi][ni][rr] + bv[ni];
        }
    }
}

// ---------------- K1c: accumulate slice_token partials + slice_norm partials ----------------
__global__ __launch_bounds__(256) void k1c_accum(
    const float* __restrict__ y, float* __restrict__ partials)
{
    int chunk = blockIdx.x & 63;
    int bh = blockIdx.x >> 6;
    int b = bh >> 3, h = bh & 7;
    long tbase = (long)b * NTOK + (long)chunk * 512;

    __shared__ float wl[8][64];
    __shared__ float fxl[8][32];

    int tid = threadIdx.x;
    int d = tid & 31;
    int sg = tid >> 5;  // 0..7

    float acc[8] = {0, 0, 0, 0, 0, 0, 0, 0};
    float nacc = 0.f;

    for (int g = 0; g < 64; ++g) {
        long t0 = tbase + g * 8;
        {
            int idx = tid;
            #pragma unroll
            for (int r = 0; r < 2; ++r, idx += 256) {
                int ti = idx >> 6, s = idx & 63;
                wl[ti][s] = y[(t0 + ti) * NCOL + 256 + h * 64 + s];
            }
            int ti = tid >> 5, dd = tid & 31;
            fxl[ti][dd] = y[(t0 + ti) * NCOL + h * 32 + dd];
        }
        __syncthreads();
        #pragma unroll
        for (int ti = 0; ti < 8; ++ti) {
            float f = fxl[ti][d];
            #pragma unroll
            for (int k = 0; k < 8; ++k)
                acc[k] += wl[ti][sg + 8 * k] * f;
        }
        if (tid < 64) {
            #pragma unroll
            for (int ti = 0; ti < 8; ++ti) nacc += wl[ti][tid];
        }
        __syncthreads();
    }

    float* P = partials + ((long)bh * 64 + chunk) * 2112;
    #pragma unroll
    for (int k = 0; k < 8; ++k) {
        int s = sg + 8 * k;
        P[s * 32 + d] = acc[k];
    }
    if (tid < 64) P[2048 + tid] = nacc;
}

// ---------------- K3: reduce partials, slice attention, build OT2T (bf16 hi/lo) ----------------
// OT2T[b][c][k'] : k'=h*64+s -> hi, k'=512+h*64+s -> lo of
//   sum_d out_tok[b,h,s,d] * Wout[c][h*32+d]
__global__ __launch_bounds__(256) void k3_slice(
    const float* __restrict__ partials,
    const float* __restrict__ Wqkv,
    const float* __restrict__ Wout,
    __bf16* __restrict__ OT2T)
{
    __shared__ float smem[14720];
    float* st = smem;          // 64*33
    float* q  = smem + 2112;
    float* kk = smem + 4224;
    float* v  = smem + 6336;
    float* L  = smem + 8448;   // 64*65
    float* red = L;
    float* ot = smem + 12608;  // 64*33

    int bh = blockIdx.x;
    int b = bh >> 3, h = bh & 7;
    int tid = threadIdx.x;

    for (int idx = tid; idx < 2112; idx += 256) {
        float s = 0.f;
        const float* P = partials + (long)bh * 64 * 2112 + idx;
        for (int c = 0; c < 64; ++c) s += P[c * 2112];
        red[idx] = s;
    }
    __syncthreads();
    for (int idx = tid; idx < 2048; idx += 256) {
        int s = idx >> 5, d = idx & 31;
        st[s * 33 + d] = red[idx] / (red[2048 + s] + 0.01f);
    }
    __syncthreads();
    for (int idx = tid; idx < 64 * 96; idx += 256) {
        int s = idx / 96, e = idx % 96;
        float acc = 0.f;
        #pragma unroll
        for (int d = 0; d < 32; ++d) acc += st[s * 33 + d] * Wqkv[e * 32 + d];
        if (e < 32)       q[s * 33 + e] = acc;
        else if (e < 64)  kk[s * 33 + (e - 32)] = acc;
        else              v[s * 33 + (e - 64)] = acc;
    }
    __syncthreads();
    for (int idx = tid; idx < 4096; idx += 256) {
        int i = idx >> 6, j = idx & 63;
        float acc = 0.f;
        #pragma unroll
        for (int d = 0; d < 32; ++d) acc += q[i * 33 + d] * kk[j * 33 + d];
        L[i * 65 + j] = acc * 0.17677669529663687f;
    }
    __syncthreads();
    {
        int lane = tid & 63, wid = tid >> 6;
        for (int r = wid; r < 64; r += 4) {
            float x = L[r * 65 + lane];
            float m = x;
            #pragma unroll
            for (int o = 32; o; o >>= 1) m = fmaxf(m, __shfl_xor(m, o));
            float e = __expf(x - m);
            float ss2 = e;
            #pragma unroll
            for (int o = 32; o; o >>= 1) ss2 += __shfl_xor(ss2, o);
            L[r * 65 + lane] = e / ss2;
        }
    }
    __syncthreads();
    for (int idx = tid; idx < 2048; idx += 256) {
        int s = idx >> 5, d = idx & 31;
        float acc = 0.f;
        #pragma unroll
        for (int j = 0; j < 64; ++j) acc += L[s * 65 + j] * v[j * 33 + d];
        ot[s * 33 + d] = acc;
    }
    __syncthreads();
    float* Wo = smem;  // 256*33
    for (int idx = tid; idx < 8192; idx += 256) {
        int c = idx >> 5, d = idx & 31;
        Wo[c * 33 + d] = Wout[c * 256 + h * 32 + d];
    }
    __syncthreads();
    {
        int c = tid;
        __bf16* O = OT2T + (long)b * 262144 + (long)c * 1024 + h * 64;
        for (int s = 0; s < 64; ++s) {
            float acc = 0.f;
            #pragma unroll
            for (int d = 0; d < 32; ++d) acc += ot[s * 33 + d] * Wo[c * 33 + d];
            __bf16 hi = (__bf16)acc;
            O[s] = hi;
            O[512 + s] = (__bf16)(acc - (float)hi);
        }
    }
}

extern "C" void kernel_launch(void* const* d_in, const int* in_sizes, int n_in,
                              void* d_out, int out_size, void* d_ws, size_t ws_size,
                              hipStream_t stream) {
    const float* x           = (const float*)d_in[0];
    const float* Wx          = (const float*)d_in[1];
    const float* bx          = (const float*)d_in[2];
    const float* Wfx         = (const float*)d_in[3];
    const float* bfx         = (const float*)d_in[4];
    const float* Wslice      = (const float*)d_in[5];
    const float* bslice      = (const float*)d_in[6];
    const float* Wqkv        = (const float*)d_in[7];
    const float* Wout        = (const float*)d_in[8];
    const float* bout        = (const float*)d_in[9];
    const float* temperature = (const float*)d_in[10];
    float* out = (float*)d_out;

    char* ws = (char*)d_ws;
    float*  y        = (float*)(ws);                                  // 131072*768 f32
    float*  partials = (float*)(ws + 402653184ULL);                   // 32*64*2112 f32
    __bf16* BtK1a    = (__bf16*)(ws + 402653184ULL + 17301504ULL);    // 768*512 bf16
    float*  bcomb    = (float*)(ws + 402653184ULL + 17301504ULL + 786432ULL);  // 768 f32
    __bf16* OT2T     = (__bf16*)(ws + 402653184ULL + 17301504ULL + 786432ULL + 3072ULL); // 4*256*1024 bf16

    // K0: combined weights (bf16 hi/lo, [n][k] layout)
    k0_build<<<768, 256, 0, stream>>>(Wx, bx, Wfx, bfx, Wslice, bslice, BtK1a, bcomb);

    // K1a: y = x @ Bcomb + bcomb, softmax fused on proj cols (M=131072, N=768, K=256)
    gemm_split<4, true><<<dim3(NCOL / 128, BNT / 128), 256, 0, stream>>>(
        x, BtK1a, bcomb, y, temperature, CDIM, NCOL, 0L);

    // K1c: pooled partial sums
    k1c_accum<<<32 * 64, 256, 0, stream>>>(y, partials);

    // K3: slice attention + OT2T (bf16 hi/lo transposed)
    k3_slice<<<32, 256, 0, stream>>>(partials, Wqkv, Wout, OT2T);

    // K4: out = w @ OT2 + bout  (M=131072, N=256, K=512) split-bf16 MFMA
    gemm_split<8, false><<<dim3(256 / 128, BNT / 128), 256, 0, stream>>>(
        y + 256, OT2T, bout, out, nullptr, NCOL, 256, 262144L);
}